// Round 7
// baseline (1210.489 us; speedup 1.0000x reference)
//
#include <hip/hip_runtime.h>
#include <cstdint>
#include <cfloat>
#include <cstddef>

#define MAXK 128
#define FCAP 256
#define DLT 4e-3f

typedef __attribute__((ext_vector_type(8))) short bf16x8;
typedef __attribute__((ext_vector_type(4))) float f32x4;

// ---------------------------------------------------------------------------
// split 8 fp32 -> hi-bf16 x8 (uint4) + lo-bf16 x8 (uint4)
// ---------------------------------------------------------------------------
__device__ __forceinline__ void split8(const float4& v0, const float4& v1,
                                       uint4& hp, uint4& lp)
{
    float vv[8] = {v0.x, v0.y, v0.z, v0.w, v1.x, v1.y, v1.z, v1.w};
    unsigned h[8], l[8];
    #pragma unroll
    for (int i = 0; i < 8; ++i) {
        unsigned u  = __float_as_uint(vv[i]);
        unsigned hb = u & 0xFFFF0000u;
        float lf    = vv[i] - __uint_as_float(hb);
        h[i] = u;
        l[i] = __float_as_uint(lf);
    }
    hp.x = (h[0] >> 16) | (h[1] & 0xFFFF0000u);
    hp.y = (h[2] >> 16) | (h[3] & 0xFFFF0000u);
    hp.z = (h[4] >> 16) | (h[5] & 0xFFFF0000u);
    hp.w = (h[6] >> 16) | (h[7] & 0xFFFF0000u);
    lp.x = (l[0] >> 16) | (l[1] & 0xFFFF0000u);
    lp.y = (l[2] >> 16) | (l[3] & 0xFFFF0000u);
    lp.z = (l[4] >> 16) | (l[5] & 0xFFFF0000u);
    lp.w = (l[6] >> 16) | (l[7] & 0xFFFF0000u);
}

// async global -> LDS, 16B per lane. LDS dest = wave-uniform base + lane*16.
__device__ __forceinline__ void gload_lds16(const void* g, void* l)
{
    __builtin_amdgcn_global_load_lds(
        (const __attribute__((address_space(1))) unsigned int*)g,
        (__attribute__((address_space(3))) unsigned int*)l,
        16, 0, 0);
}

// ---------------------------------------------------------------------------
// Monotonic uint key for float ordering
// ---------------------------------------------------------------------------
__device__ __forceinline__ unsigned fkey(float f)
{
    unsigned u = __float_as_uint(f);
    return u ^ ((unsigned)((int)u >> 31) | 0x80000000u);
}
__device__ __forceinline__ float finv(unsigned k)
{
    unsigned u = (k & 0x80000000u) ? (k ^ 0x80000000u) : ~k;
    return __uint_as_float(u);
}

// exact fp32 dot for feature f over one wave; valid result on ln==0 only
__device__ __forceinline__ float exact_zpre(const float* __restrict__ xr,
                                            const float* __restrict__ Wenc,
                                            const float* __restrict__ b_enc,
                                            const float* __restrict__ b_dec,
                                            int f, int D, int ln)
{
    const float* wr = Wenc + (size_t)f * D;
    float s = 0.f;
    for (int d = ln * 4; d < D; d += 256) {
        float4 xv = *(const float4*)(xr + d);
        float4 bd = *(const float4*)(b_dec + d);
        float4 wv4 = *(const float4*)(wr + d);
        s = fmaf(xv.x - bd.x, wv4.x, s);
        s = fmaf(xv.y - bd.y, wv4.y, s);
        s = fmaf(xv.z - bd.z, wv4.z, s);
        s = fmaf(xv.w - bd.w, wv4.w, s);
    }
    #pragma unroll
    for (int o = 32; o > 0; o >>= 1) s += __shfl_down(s, o, 64);
    return s + b_enc[f];
}

// ---------------------------------------------------------------------------
// prep_x: (x - b_dec) -> split bf16 hi/lo, tile-packed + pre-swizzled.
// ---------------------------------------------------------------------------
__global__ __launch_bounds__(256)
void prep_x_kernel(const float* __restrict__ x, const float* __restrict__ b_dec,
                   ushort* __restrict__ AhiP, ushort* __restrict__ AloP, int D)
{
    const int c   = blockIdx.x * 256 + threadIdx.x;
    const int t   = c >> 9;
    const int wc  = c & 511;
    const int rl  = wc >> 2;
    const int pkc = wc & 3;
    const int kc  = (pkc - (rl >> 1)) & 3;
    const int nkb = D >> 5;
    const int band = t / nkb, kblk = t - band * nkb;
    const int row = band * 128 + rl;
    const int k0  = kblk * 32 + kc * 8;

    const float* src = x + (size_t)row * D + k0;
    float4 v0 = *(const float4*)(src);
    float4 v1 = *(const float4*)(src + 4);
    const float* bd = b_dec + k0;
    float4 d0 = *(const float4*)(bd);
    float4 d1 = *(const float4*)(bd + 4);
    v0.x -= d0.x; v0.y -= d0.y; v0.z -= d0.z; v0.w -= d0.w;
    v1.x -= d1.x; v1.y -= d1.y; v1.z -= d1.z; v1.w -= d1.w;
    uint4 hp, lp;
    split8(v0, v1, hp, lp);
    const size_t off = (size_t)t * 4096 + (size_t)wc * 8;
    *(uint4*)&AhiP[off] = hp;
    *(uint4*)&AloP[off] = lp;
}

// ---------------------------------------------------------------------------
// prep_w: W_enc -> split bf16 hi/lo, tile-packed + pre-swizzled.
// ---------------------------------------------------------------------------
__global__ __launch_bounds__(256)
void prep_w_kernel(const float* __restrict__ Wenc,
                   ushort* __restrict__ WhiP, ushort* __restrict__ WloP, int D)
{
    const int c   = blockIdx.x * 256 + threadIdx.x;
    const int t   = c >> 10;
    const int wc  = c & 1023;
    const int rl  = wc >> 2;
    const int pkc = wc & 3;
    const int kc  = (pkc - (rl >> 1)) & 3;
    const int nkb = D >> 5;
    const int fband = t / nkb, kblk = t - fband * nkb;
    const int f   = fband * 256 + rl;
    const int k0  = kblk * 32 + kc * 8;

    const float* src = Wenc + (size_t)f * D + k0;
    float4 v0 = *(const float4*)(src);
    float4 v1 = *(const float4*)(src + 4);
    uint4 hp, lp;
    split8(v0, v1, hp, lp);
    const size_t off = (size_t)t * 8192 + (size_t)wc * 8;
    *(uint4*)&WhiP[off] = hp;
    *(uint4*)&WloP[off] = lp;
}

// ---------------------------------------------------------------------------
// tau_kernel: per-row sigma from ||x - b_dec|| (W_enc-norm concentration),
// Gaussian-tail threshold for ~160 expected candidates. Also zeroes the
// per-row candidate counter. Sentinel (tau=-1, taulo=+inf) if assumptions
// don't hold -> topk_select falls back to radix for every row.
// ---------------------------------------------------------------------------
__global__ __launch_bounds__(256)
void tau_kernel(const float* __restrict__ x, const float* __restrict__ b_dec,
                const int* __restrict__ k_ptr,
                float* __restrict__ tau_arr, float* __restrict__ taulo_arr,
                int* __restrict__ ccnt, int F, int D)
{
    const int row = blockIdx.x, t = threadIdx.x;
    const int wv_id = t >> 6, ln = t & 63;
    __shared__ float s2w[4];

    float s2 = 0.f;
    for (int d = t * 4; d < D; d += 1024) {
        float4 xv = *(const float4*)(x + (size_t)row * D + d);
        float4 bd = *(const float4*)(b_dec + d);
        const float a = xv.x - bd.x, b = xv.y - bd.y;
        const float c = xv.z - bd.z, e = xv.w - bd.w;
        s2 = fmaf(a, a, s2); s2 = fmaf(b, b, s2);
        s2 = fmaf(c, c, s2); s2 = fmaf(e, e, s2);
    }
    #pragma unroll
    for (int o = 32; o > 0; o >>= 1) s2 += __shfl_down(s2, o, 64);
    if (ln == 0) s2w[wv_id] = s2;
    __syncthreads();

    if (t == 0) {
        const int k = *k_ptr;
        const float sig = sqrtf((s2w[0] + s2w[1] + s2w[2] + s2w[3]) / (float)D);
        float tau, taulo;
        if (k <= 40 && F >= 4096 && sig > 1e-4f) {
            const float qq  = 160.f / (float)F;
            const float tt  = sqrtf(-2.f * logf(qq));
            const float phi = tt - (2.30753f + 0.27061f * tt) /
                                   (1.f + 0.99229f * tt + 0.04481f * tt * tt);
            tau   = sig * phi;
            taulo = tau - 0.03f * sig;
        } else {
            tau = -1.f; taulo = FLT_MAX;     // force fallback
        }
        tau_arr[row]   = tau;
        taulo_arr[row] = taulo;
        ccnt[row]      = 0;
    }
}

// ---------------------------------------------------------------------------
// zfill: dense zero-fill of z (compulsory output traffic).
// ---------------------------------------------------------------------------
__global__ __launch_bounds__(256)
void zfill_kernel(float4* __restrict__ p, long n4)
{
    const float4 zz = make_float4(0.f, 0.f, 0.f, 0.f);
    const long stride = (long)gridDim.x * 256;
    for (long i = (long)blockIdx.x * 256 + threadIdx.x; i < n4; i += stride)
        p[i] = zz;
}

// ---------------------------------------------------------------------------
// Encode GEMM with fused candidate filter. Same GEMM structure as the proven
// round-6 kernel (A single-buffered, B double-buffered, 80 KB, 2 blocks/CU).
// Epilogue additionally appends (val, idx) of values > taulo[row] to the
// per-row candidate buffer (cap FCAP; count keeps incrementing past cap so
// overflow is detectable).
// ---------------------------------------------------------------------------
__global__ __launch_bounds__(256, 2)
void encode_gemm_filter(const ushort* __restrict__ AhiP, const ushort* __restrict__ AloP,
                        const ushort* __restrict__ WhiP, const ushort* __restrict__ WloP,
                        const float* __restrict__ b_enc, float* __restrict__ z_pre,
                        const float* __restrict__ taulo_arr,
                        int* __restrict__ ccnt, float* __restrict__ cvalB,
                        int* __restrict__ cidxB, int D, int F)
{
    __shared__ ushort AsHi[4096];
    __shared__ ushort AsLo[4096];
    __shared__ ushort BsHi[2][8192];
    __shared__ ushort BsLo[2][8192];

    const int tid = threadIdx.x;
    const int bm  = blockIdx.y * 128;
    const int bn  = blockIdx.x * 256;

    const int lane = tid & 63;
    const int w    = tid >> 6;
    const int wm   = (w >> 1) * 64;
    const int wn   = (w & 1) * 128;
    const int fr   = lane & 15;
    const int q    = lane >> 4;
    const int nkb  = D >> 5;

    int aoff[4], boff[8];
    #pragma unroll
    for (int mi = 0; mi < 4; ++mi) {
        const int r = wm + mi * 16 + fr;
        aoff[mi] = r * 32 + (((q + (r >> 1)) & 3) * 8);
    }
    #pragma unroll
    for (int ni = 0; ni < 8; ++ni) {
        const int r = wn + ni * 16 + fr;
        boff[ni] = r * 32 + (((q + (r >> 1)) & 3) * 8);
    }

    f32x4 acc[4][8];
    #pragma unroll
    for (int mi = 0; mi < 4; ++mi)
        #pragma unroll
        for (int ni = 0; ni < 8; ++ni)
            acc[mi][ni] = (f32x4){0.f, 0.f, 0.f, 0.f};

    const char* aHi = (const char*)AhiP + (size_t)blockIdx.y * nkb * 8192;
    const char* aLo = (const char*)AloP + (size_t)blockIdx.y * nkb * 8192;
    const char* bHi = (const char*)WhiP + (size_t)blockIdx.x * nkb * 16384;
    const char* bLo = (const char*)WloP + (size_t)blockIdx.x * nkb * 16384;
    const int la16 = lane * 16;

    auto stageA = [&](int kb) {
        const char* pa = aHi + (size_t)kb * 8192;
        const char* pl = aLo + (size_t)kb * 8192;
        #pragma unroll
        for (int c = 0; c < 2; ++c) {
            const int off = (w * 2 + c) * 1024;
            gload_lds16(pa + off + la16, (char*)AsHi + off);
            gload_lds16(pl + off + la16, (char*)AsLo + off);
        }
    };
    auto stageB = [&](int kb, int buf) {
        const char* pb = bHi + (size_t)kb * 16384;
        const char* pm = bLo + (size_t)kb * 16384;
        #pragma unroll
        for (int c = 0; c < 4; ++c) {
            const int off = (w * 4 + c) * 1024;
            gload_lds16(pb + off + la16, (char*)&BsHi[buf][0] + off);
            gload_lds16(pm + off + la16, (char*)&BsLo[buf][0] + off);
        }
    };

    stageA(0);
    stageB(0, 0);
    asm volatile("s_waitcnt vmcnt(0)" ::: "memory");
    __syncthreads();

    int cur = 0;
    for (int kb = 0; kb < nkb; ++kb) {
        bf16x8 ahi[4], alo[4];
        #pragma unroll
        for (int mi = 0; mi < 4; ++mi) {
            ahi[mi] = *(const bf16x8*)&AsHi[aoff[mi]];
            alo[mi] = *(const bf16x8*)&AsLo[aoff[mi]];
        }
        __syncthreads();
        if (kb + 1 < nkb) {
            stageA(kb + 1);
            stageB(kb + 1, cur ^ 1);
        }
        const ushort* sBH = &BsHi[cur][0];
        const ushort* sBL = &BsLo[cur][0];
        #pragma unroll
        for (int ni = 0; ni < 8; ++ni) {
            bf16x8 bhi = *(const bf16x8*)&sBH[boff[ni]];
            bf16x8 blo = *(const bf16x8*)&sBL[boff[ni]];
            #pragma unroll
            for (int mi = 0; mi < 4; ++mi) {
                acc[mi][ni] = __builtin_amdgcn_mfma_f32_16x16x32_bf16(alo[mi], bhi, acc[mi][ni], 0, 0, 0);
                acc[mi][ni] = __builtin_amdgcn_mfma_f32_16x16x32_bf16(ahi[mi], blo, acc[mi][ni], 0, 0, 0);
                acc[mi][ni] = __builtin_amdgcn_mfma_f32_16x16x32_bf16(ahi[mi], bhi, acc[mi][ni], 0, 0, 0);
            }
        }
        asm volatile("s_waitcnt vmcnt(0)" ::: "memory");
        __syncthreads();
        cur ^= 1;
    }

    // tau_lo per (mi, r) row handled by this thread (16 rows, L2-hot)
    float tlo[4][4];
    #pragma unroll
    for (int mi = 0; mi < 4; ++mi)
        #pragma unroll
        for (int r = 0; r < 4; ++r)
            tlo[mi][r] = taulo_arr[bm + wm + mi * 16 + q * 4 + r];

    // epilogue: +b_enc, store z_pre, filter candidates
    #pragma unroll
    for (int ni = 0; ni < 8; ++ni) {
        const int col = bn + wn + ni * 16 + fr;
        const float be = b_enc[col];
        #pragma unroll
        for (int mi = 0; mi < 4; ++mi) {
            const int rbase = bm + wm + mi * 16 + q * 4;
            float* dst = z_pre + (size_t)rbase * F + col;
            #pragma unroll
            for (int r = 0; r < 4; ++r) {
                const float val = acc[mi][ni][r] + be;
                dst[(size_t)r * F] = val;
                if (val > tlo[mi][r]) {
                    const int rowi = rbase + r;
                    const int s = atomicAdd(&ccnt[rowi], 1);
                    if (s < FCAP) {
                        cvalB[(size_t)rowi * FCAP + s] = val;
                        cidxB[(size_t)rowi * FCAP + s] = col;
                    }
                }
            }
        }
    }
}

// ---------------------------------------------------------------------------
// topk_select: per-row selection from the candidate buffer (no z_pre stream).
// Fast path identical semantics to previous rounds (approx rank, sure-select
// above vk+DLT, exact recompute of +-DLT boundary, serial pick, scatter).
// Fallback (counter overflow / tau sentinel / too-few candidates): 2-pass
// radix on global z_pre. z already zero-filled by zfill_kernel.
// ---------------------------------------------------------------------------
__global__ __launch_bounds__(256)
void topk_select(const float* __restrict__ z_pre, float* __restrict__ z,
                 float* __restrict__ ws_vals, int* __restrict__ ws_idx,
                 const int* __restrict__ k_ptr,
                 const float* __restrict__ x, const float* __restrict__ Wenc,
                 const float* __restrict__ b_enc, const float* __restrict__ b_dec,
                 const float* __restrict__ tau_arr, const int* __restrict__ ccnt,
                 const float* __restrict__ cvalB, const int* __restrict__ cidxB,
                 int F, int D)
{
    const int row = blockIdx.x;
    const int t   = threadIdx.x;
    const int k   = *k_ptr;
    const int wv_id = t >> 6, ln = t & 63;

    __shared__ float cand_v[FCAP];
    __shared__ int   cand_i[FCAP];
    __shared__ unsigned char cand_sel[FCAP];
    __shared__ int   bnd[128];
    __shared__ int   hist4[4][256];
    __shared__ int   waveTot[4];
    __shared__ int   s_bin, s_above;
    __shared__ int   n_b_s, c_hi_s, out_cnt, cnt_tau_s, bad_s, n_c_s;
    __shared__ unsigned vk_key;

    if (t == 0) {
        n_b_s = 0; c_hi_s = 0; out_cnt = 0; cnt_tau_s = 0; bad_s = 0;
        vk_key = 0xFFFFFFFFu;
    }
    __syncthreads();

    const float tau = tau_arr[row];
    const int cnt   = ccnt[row];
    if (t == 0 && (cnt > FCAP || !(tau > 0.1f))) bad_s = 1;
    const int n_c = min(cnt, FCAP);

    const float* zrow = z_pre + (size_t)row * F;
    float* wvp = ws_vals + (size_t)row * MAXK;
    int*   wip = ws_idx  + (size_t)row * MAXK;

    float myv = -FLT_MAX;
    cand_sel[t] = 0;
    if (t < n_c) {
        myv = cvalB[(size_t)row * FCAP + t];
        cand_v[t] = myv;
        cand_i[t] = cidxB[(size_t)row * FCAP + t];
        if (myv > tau) atomicAdd(&cnt_tau_s, 1);
    }
    __syncthreads();
    if (t == 0 && cnt_tau_s < k) bad_s = 1;

    // rank among candidates (approx) -> kth largest
    if (t < n_c) {
        int gt = 0;
        for (int j = 0; j < n_c; ++j) gt += (cand_v[j] > myv);
        if (gt <= k - 1) atomicMin(&vk_key, fkey(myv));
    }
    __syncthreads();

    const float vkv = finv(vk_key);
    if (t < n_c) {
        if (myv > vkv + DLT) {
            cand_sel[t] = 2;
            atomicAdd(&c_hi_s, 1);
        } else if (myv > vkv - DLT) {
            const int sb = atomicAdd(&n_b_s, 1);
            if (sb < 128) bnd[sb] = t;
        }
    }
    __syncthreads();
    if (t == 0 && n_b_s > 128) bad_s = 1;
    __syncthreads();

    if (!bad_s) {
        const int n_b = n_b_s;
        const float* xr = x + (size_t)row * D;
        for (int b2 = wv_id; b2 < n_b; b2 += 4) {
            const int c = bnd[b2];
            const float ex = exact_zpre(xr, Wenc, b_enc, b_dec, cand_i[c], D, ln);
            if (ln == 0) cand_v[c] = ex;
        }
        __syncthreads();

        if (t == 0) {
            int need = k - c_hi_s;
            if (need > n_b) need = n_b;
            for (int it = 0; it < need; ++it) {
                int bi = -1; float bv = 0.f;
                for (int b2 = 0; b2 < n_b; ++b2) {
                    const int c = bnd[b2];
                    if (cand_sel[c]) continue;
                    const float v = cand_v[c];
                    if (bi < 0 || v > bv || (v == bv && cand_i[c] < cand_i[bi])) {
                        bi = c; bv = v;
                    }
                }
                if (bi < 0) break;
                cand_sel[bi] = 1;
            }
        }
        __syncthreads();

        if (t < n_c && cand_sel[t]) {
            const float zv = fmaxf(cand_v[t], 0.f);
            z[(size_t)row * F + cand_i[t]] = zv;
            const int s = atomicAdd(&out_cnt, 1);
            if (s < MAXK) { wvp[s] = zv; wip[s] = cand_i[t]; }
        }
        return;
    }

    // ================= fallback: 2-pass radix on global z_pre ===============
    if (t == 0) { n_c_s = 0; c_hi_s = 0; out_cnt = 0; }
    __syncthreads();

    unsigned prefix = 0;
    int rem = k;
    for (int pass = 0; pass < 2; ++pass) {
        const int shift = 24 - 8 * pass;
        hist4[0][t] = 0; hist4[1][t] = 0; hist4[2][t] = 0; hist4[3][t] = 0;
        __syncthreads();
        for (int j = t; j < F; j += 256) {
            const unsigned key = fkey(zrow[j]);
            const bool inb = (pass == 0) || ((key >> (shift + 8)) == prefix);
            if (inb) atomicAdd(&hist4[wv_id][(key >> shift) & 255], 1);
        }
        __syncthreads();
        const int cnt2 = hist4[0][t] + hist4[1][t] + hist4[2][t] + hist4[3][t];
        int s = cnt2;
        #pragma unroll
        for (int off = 1; off < 64; off <<= 1) {
            const int tmp = __shfl_down(s, off, 64);
            if (ln + off < 64) s += tmp;
        }
        if (ln == 0) waveTot[wv_id] = s;
        __syncthreads();
        int add = 0;
        #pragma unroll
        for (int w2 = 0; w2 < 4; ++w2)
            if (w2 > wv_id) add += waveTot[w2];
        const int sfx = s + add;
        const int nxt = sfx - cnt2;
        if (sfx >= rem && nxt < rem) { s_bin = t; s_above = nxt; }
        __syncthreads();
        rem -= s_above;
        prefix = (prefix << 8) | (unsigned)s_bin;
        __syncthreads();
    }

    const float hiT = finv((prefix << 16) | 0xFFFFu) + DLT;
    const float loT = finv(prefix << 16) - DLT;

    for (int j = t; j < F; j += 256) {
        const float v = zrow[j];
        if (v > hiT) atomicAdd(&c_hi_s, 1);
        else if (v > loT) {
            const int s = atomicAdd(&n_c_s, 1);
            if (s < FCAP) { cand_i[s] = j; cand_sel[s] = 0; }
        }
    }
    __syncthreads();
    const int n_c2 = min(n_c_s, FCAP);

    {
        const float* xr = x + (size_t)row * D;
        for (int c = wv_id; c < n_c2; c += 4) {
            const float ex = exact_zpre(xr, Wenc, b_enc, b_dec, cand_i[c], D, ln);
            if (ln == 0) cand_v[c] = ex;
        }
    }
    __syncthreads();

    if (t == 0) {
        int need = k - c_hi_s;
        if (need > n_c2) need = n_c2;
        for (int it = 0; it < need; ++it) {
            int bi = -1; float bv = 0.f;
            for (int c = 0; c < n_c2; ++c) {
                if (cand_sel[c]) continue;
                const float v = cand_v[c];
                if (bi < 0 || v > bv || (v == bv && cand_i[c] < cand_i[bi])) {
                    bi = c; bv = v;
                }
            }
            if (bi < 0) break;
            cand_sel[bi] = 1;
        }
    }
    __syncthreads();

    for (int j = t; j < F; j += 256) {
        const float v = zrow[j];
        if (v > hiT) {
            const float zv = fmaxf(v, 0.f);
            z[(size_t)row * F + j] = zv;
            const int s = atomicAdd(&out_cnt, 1);
            if (s < MAXK) { wvp[s] = zv; wip[s] = j; }
        }
    }
    if (t < n_c2 && cand_sel[t]) {
        const float zv = fmaxf(cand_v[t], 0.f);
        z[(size_t)row * F + cand_i[t]] = zv;
        const int s = atomicAdd(&out_cnt, 1);
        if (s < MAXK) { wvp[s] = zv; wip[s] = cand_i[t]; }
    }
}

// ---------------------------------------------------------------------------
// Pre-split GEMM without filter (workspace-limited path).
// ---------------------------------------------------------------------------
__global__ __launch_bounds__(256, 2)
void encode_gemm_pre(const ushort* __restrict__ AhiP, const ushort* __restrict__ AloP,
                     const ushort* __restrict__ WhiP, const ushort* __restrict__ WloP,
                     const float* __restrict__ b_enc, float* __restrict__ z_pre,
                     int D, int F)
{
    __shared__ ushort AsHi[4096];
    __shared__ ushort AsLo[4096];
    __shared__ ushort BsHi[8192];
    __shared__ ushort BsLo[8192];

    const int tid = threadIdx.x;
    const int bm  = blockIdx.y * 128;
    const int bn  = blockIdx.x * 256;

    const int lane = tid & 63;
    const int w    = tid >> 6;
    const int wm   = (w >> 1) * 64;
    const int wn   = (w & 1) * 128;
    const int fr   = lane & 15;
    const int q    = lane >> 4;
    const int nkb  = D >> 5;

    int aoff[4], boff[8];
    #pragma unroll
    for (int mi = 0; mi < 4; ++mi) {
        const int r = wm + mi * 16 + fr;
        aoff[mi] = r * 32 + (((q + (r >> 1)) & 3) * 8);
    }
    #pragma unroll
    for (int ni = 0; ni < 8; ++ni) {
        const int r = wn + ni * 16 + fr;
        boff[ni] = r * 32 + (((q + (r >> 1)) & 3) * 8);
    }

    f32x4 acc[4][8];
    #pragma unroll
    for (int mi = 0; mi < 4; ++mi)
        #pragma unroll
        for (int ni = 0; ni < 8; ++ni)
            acc[mi][ni] = (f32x4){0.f, 0.f, 0.f, 0.f};

    const char* aHi = (const char*)AhiP + (size_t)blockIdx.y * nkb * 8192;
    const char* aLo = (const char*)AloP + (size_t)blockIdx.y * nkb * 8192;
    const char* bHi = (const char*)WhiP + (size_t)blockIdx.x * nkb * 16384;
    const char* bLo = (const char*)WloP + (size_t)blockIdx.x * nkb * 16384;
    const int la16 = lane * 16;

    for (int kb = 0; kb < nkb; ++kb) {
        const char* pa = aHi + (size_t)kb * 8192;
        const char* pl = aLo + (size_t)kb * 8192;
        const char* pb = bHi + (size_t)kb * 16384;
        const char* pm = bLo + (size_t)kb * 16384;

        #pragma unroll
        for (int c = 0; c < 2; ++c) {
            const int off = (w * 2 + c) * 1024;
            gload_lds16(pa + off + la16, (char*)AsHi + off);
            gload_lds16(pl + off + la16, (char*)AsLo + off);
        }
        #pragma unroll
        for (int c = 0; c < 4; ++c) {
            const int off = (w * 4 + c) * 1024;
            gload_lds16(pb + off + la16, (char*)BsHi + off);
            gload_lds16(pm + off + la16, (char*)BsLo + off);
        }
        asm volatile("s_waitcnt vmcnt(0)" ::: "memory");
        __syncthreads();

        bf16x8 ahi[4], alo[4];
        #pragma unroll
        for (int mi = 0; mi < 4; ++mi) {
            ahi[mi] = *(const bf16x8*)&AsHi[aoff[mi]];
            alo[mi] = *(const bf16x8*)&AsLo[aoff[mi]];
        }
        #pragma unroll
        for (int ni = 0; ni < 8; ++ni) {
            bf16x8 bhi = *(const bf16x8*)&BsHi[boff[ni]];
            bf16x8 blo = *(const bf16x8*)&BsLo[boff[ni]];
            #pragma unroll
            for (int mi = 0; mi < 4; ++mi) {
                acc[mi][ni] = __builtin_amdgcn_mfma_f32_16x16x32_bf16(alo[mi], bhi, acc[mi][ni], 0, 0, 0);
                acc[mi][ni] = __builtin_amdgcn_mfma_f32_16x16x32_bf16(ahi[mi], blo, acc[mi][ni], 0, 0, 0);
                acc[mi][ni] = __builtin_amdgcn_mfma_f32_16x16x32_bf16(ahi[mi], bhi, acc[mi][ni], 0, 0, 0);
            }
        }
        __syncthreads();
    }

    #pragma unroll
    for (int ni = 0; ni < 8; ++ni) {
        const int col = bn + wn + ni * 16 + fr;
        const float be = b_enc[col];
        #pragma unroll
        for (int mi = 0; mi < 4; ++mi) {
            const int rbase = bm + wm + mi * 16 + q * 4;
            float* dst = z_pre + (size_t)rbase * F + col;
            #pragma unroll
            for (int r = 0; r < 4; ++r)
                dst[(size_t)r * F] = acc[mi][ni][r] + be;
        }
    }
}

// ---------------------------------------------------------------------------
// Fallback encode GEMM (reg-staged split) — used only if workspace too small.
// ---------------------------------------------------------------------------
__global__ __launch_bounds__(256, 2)
void encode_gemm_bf16x3(const float* __restrict__ x, const float* __restrict__ Wenc,
                        const float* __restrict__ b_enc, const float* __restrict__ b_dec,
                        float* __restrict__ z_pre, int D, int F)
{
    constexpr int BM = 128, BN = 256, BK = 32;
    __shared__ ushort AsHi[BM * BK];
    __shared__ ushort AsLo[BM * BK];
    __shared__ ushort BsHi[BN * BK];
    __shared__ ushort BsLo[BN * BK];

    const int tid = threadIdx.x;
    const int bm  = blockIdx.y * BM;
    const int bn  = blockIdx.x * BN;

    const int lane = tid & 63;
    const int w    = tid >> 6;
    const int wm   = (w >> 1) * 64;
    const int wn   = (w & 1) * 128;
    const int fr   = lane & 15;
    const int q    = lane >> 4;

    int aoff[4], boff[8];
    #pragma unroll
    for (int mi = 0; mi < 4; ++mi) {
        const int r = wm + mi * 16 + fr;
        aoff[mi] = r * 32 + (((q + (r >> 1)) & 3) * 8);
    }
    #pragma unroll
    for (int ni = 0; ni < 8; ++ni) {
        const int r = wn + ni * 16 + fr;
        boff[ni] = r * 32 + (((q + (r >> 1)) & 3) * 8);
    }

    f32x4 acc[4][8];
    #pragma unroll
    for (int mi = 0; mi < 4; ++mi)
        #pragma unroll
        for (int ni = 0; ni < 8; ++ni)
            acc[mi][ni] = (f32x4){0.f, 0.f, 0.f, 0.f};

    for (int k0 = 0; k0 < D; k0 += BK) {
        #pragma unroll
        for (int j = 0; j < 2; ++j) {
            const int task = tid + 256 * j;
            const int row = task >> 2, kc = task & 3;
            const float* src = x + (size_t)(bm + row) * D + k0 + kc * 8;
            float4 v0 = *(const float4*)(src);
            float4 v1 = *(const float4*)(src + 4);
            const float* bd = b_dec + k0 + kc * 8;
            float4 d0 = *(const float4*)(bd);
            float4 d1 = *(const float4*)(bd + 4);
            v0.x -= d0.x; v0.y -= d0.y; v0.z -= d0.z; v0.w -= d0.w;
            v1.x -= d1.x; v1.y -= d1.y; v1.z -= d1.z; v1.w -= d1.w;
            uint4 hp, lp;
            split8(v0, v1, hp, lp);
            const int off = row * 32 + (((kc + (row >> 1)) & 3) * 8);
            *(uint4*)&AsHi[off] = hp;
            *(uint4*)&AsLo[off] = lp;
        }
        #pragma unroll
        for (int j = 0; j < 4; ++j) {
            const int task = tid + 256 * j;
            const int row = task >> 2, kc = task & 3;
            const float* src = Wenc + (size_t)(bn + row) * D + k0 + kc * 8;
            float4 v0 = *(const float4*)(src);
            float4 v1 = *(const float4*)(src + 4);
            uint4 hp, lp;
            split8(v0, v1, hp, lp);
            const int off = row * 32 + (((kc + (row >> 1)) & 3) * 8);
            *(uint4*)&BsHi[off] = hp;
            *(uint4*)&BsLo[off] = lp;
        }
        __syncthreads();

        bf16x8 ahi[4], alo[4];
        #pragma unroll
        for (int mi = 0; mi < 4; ++mi) {
            ahi[mi] = *(const bf16x8*)&AsHi[aoff[mi]];
            alo[mi] = *(const bf16x8*)&AsLo[aoff[mi]];
        }
        #pragma unroll
        for (int ni = 0; ni < 8; ++ni) {
            bf16x8 bhi = *(const bf16x8*)&BsHi[boff[ni]];
            bf16x8 blo = *(const bf16x8*)&BsLo[boff[ni]];
            #pragma unroll
            for (int mi = 0; mi < 4; ++mi) {
                acc[mi][ni] = __builtin_amdgcn_mfma_f32_16x16x32_bf16(alo[mi], bhi, acc[mi][ni], 0, 0, 0);
                acc[mi][ni] = __builtin_amdgcn_mfma_f32_16x16x32_bf16(ahi[mi], blo, acc[mi][ni], 0, 0, 0);
                acc[mi][ni] = __builtin_amdgcn_mfma_f32_16x16x32_bf16(ahi[mi], bhi, acc[mi][ni], 0, 0, 0);
            }
        }
        __syncthreads();
    }

    #pragma unroll
    for (int ni = 0; ni < 8; ++ni) {
        const int col = bn + wn + ni * 16 + fr;
        const float be = b_enc[col];
        #pragma unroll
        for (int mi = 0; mi < 4; ++mi) {
            const int rbase = bm + wm + mi * 16 + q * 4;
            float* dst = z_pre + (size_t)rbase * F + col;
            #pragma unroll
            for (int r = 0; r < 4; ++r)
                dst[(size_t)r * F] = acc[mi][ni][r] + be;
        }
    }
}

// ---------------------------------------------------------------------------
// topk_fast: single-stream top-k (used when filter workspace unavailable).
// ---------------------------------------------------------------------------
template <int NVEC>
__global__ __launch_bounds__(256)
void topk_fast(const float* __restrict__ z_pre, float* __restrict__ z,
               float* __restrict__ ws_vals, int* __restrict__ ws_idx,
               const int* __restrict__ k_ptr,
               const float* __restrict__ x, const float* __restrict__ Wenc,
               const float* __restrict__ b_enc, const float* __restrict__ b_dec,
               int F, int D)
{
    const int row = blockIdx.x;
    const int t   = threadIdx.x;
    const int k   = *k_ptr;
    const int nv4 = F >> 2;
    const int wv_id = t >> 6, ln = t & 63;

    __shared__ ushort keys[16384];
    __shared__ float  cand_v[256];
    __shared__ int    cand_i[256];
    __shared__ unsigned char cand_sel[256];
    __shared__ int    bnd[128];
    __shared__ float  s2w[4];
    __shared__ int    hist4[4][256];
    __shared__ int    waveTot[4];
    __shared__ int    s_bin, s_above;
    __shared__ int    n_c_s, n_b_s, c_hi_s, out_cnt, cnt_tau_s, bad_s;
    __shared__ unsigned vk_key;

    if (t == 0) {
        n_c_s = 0; n_b_s = 0; c_hi_s = 0; out_cnt = 0; cnt_tau_s = 0; bad_s = 0;
        vk_key = 0xFFFFFFFFu;
    }

    const float*  zrow = z_pre + (size_t)row * F;
    const float4* src  = (const float4*)zrow;
    float4* dstz = (float4*)(z + (size_t)row * F);
    const float4 zz = make_float4(0.f, 0.f, 0.f, 0.f);

    float s2 = 0.f;
    #pragma unroll
    for (int i = 0; i < NVEC; ++i) {
        const int p = t + 256 * i;
        if (p < nv4) {
            const float4 v = src[p];
            dstz[p] = zz;
            const unsigned k0 = fkey(v.x) >> 16;
            const unsigned k1 = fkey(v.y) >> 16;
            const unsigned k2 = fkey(v.z) >> 16;
            const unsigned k3 = fkey(v.w) >> 16;
            uint2 pk;
            pk.x = k0 | (k1 << 16);
            pk.y = k2 | (k3 << 16);
            *(uint2*)&keys[p * 4] = pk;
            s2 = fmaf(v.x, v.x, s2);
            s2 = fmaf(v.y, v.y, s2);
            s2 = fmaf(v.z, v.z, s2);
            s2 = fmaf(v.w, v.w, s2);
        }
    }
    #pragma unroll
    for (int o = 32; o > 0; o >>= 1) s2 += __shfl_down(s2, o, 64);
    if (ln == 0) s2w[wv_id] = s2;
    __syncthreads();

    const float sigma = sqrtf((s2w[0] + s2w[1] + s2w[2] + s2w[3]) / (float)F);
    int c0 = 4 * k; if (c0 < 64) c0 = 64; if (c0 > 192) c0 = 192;
    const float qq  = (float)c0 / (float)F;
    const float tt  = sqrtf(-2.f * logf(qq));
    const float phi = tt - (2.30753f + 0.27061f * tt) /
                           (1.f + 0.99229f * tt + 0.04481f * tt * tt);
    const float tau = sigma * phi;
    const unsigned tk = fkey(tau) >> 16;
    const unsigned tkey16 = (tk >= 2) ? (tk - 2) : 0;

    const int nU = nv4 * 2;
    const unsigned* keysU = (const unsigned*)keys;
    for (int j = t; j < nU; j += 256) {
        const unsigned pr = keysU[j];
        const unsigned ka = pr & 0xFFFFu, kb = pr >> 16;
        if (ka > tkey16) { const int s = atomicAdd(&n_c_s, 1); if (s < 256) cand_i[s] = 2 * j; }
        if (kb > tkey16) { const int s = atomicAdd(&n_c_s, 1); if (s < 256) cand_i[s] = 2 * j + 1; }
    }
    __syncthreads();

    if (t == 0 && (n_c_s > 256 || !(tau > 0.1f))) bad_s = 1;
    const int n_c = min(n_c_s, 256);

    float myv = 0.f;
    if (t < n_c) {
        myv = zrow[cand_i[t]];
        cand_v[t] = myv;
        if (myv > tau) atomicAdd(&cnt_tau_s, 1);
    }
    __syncthreads();
    if (t == 0 && cnt_tau_s < k) bad_s = 1;

    cand_sel[t] = 0;
    if (t < n_c) {
        int gt = 0;
        for (int j = 0; j < n_c; ++j) gt += (cand_v[j] > myv);
        if (gt <= k - 1) atomicMin(&vk_key, fkey(myv));
    }
    __syncthreads();

    const float vkv = finv(vk_key);
    if (t < n_c) {
        if (myv > vkv + DLT) {
            cand_sel[t] = 2;
            atomicAdd(&c_hi_s, 1);
        } else if (myv > vkv - DLT) {
            const int sb = atomicAdd(&n_b_s, 1);
            if (sb < 128) bnd[sb] = t;
        }
    }
    __syncthreads();
    if (t == 0 && n_b_s > 128) bad_s = 1;
    __syncthreads();

    if (!bad_s) {
        const int n_b = n_b_s;
        const float* xr = x + (size_t)row * D;
        for (int b2 = wv_id; b2 < n_b; b2 += 4) {
            const int c = bnd[b2];
            const float ex = exact_zpre(xr, Wenc, b_enc, b_dec, cand_i[c], D, ln);
            if (ln == 0) cand_v[c] = ex;
        }
        __syncthreads();

        if (t == 0) {
            int need = k - c_hi_s;
            if (need > n_b) need = n_b;
            for (int it = 0; it < need; ++it) {
                int bi = -1; float bv = 0.f;
                for (int b2 = 0; b2 < n_b; ++b2) {
                    const int c = bnd[b2];
                    if (cand_sel[c]) continue;
                    const float v = cand_v[c];
                    if (bi < 0 || v > bv || (v == bv && cand_i[c] < cand_i[bi])) {
                        bi = c; bv = v;
                    }
                }
                if (bi < 0) break;
                cand_sel[bi] = 1;
            }
        }
        __syncthreads();

        float* wvp = ws_vals + (size_t)row * MAXK;
        int*   wip = ws_idx  + (size_t)row * MAXK;
        if (t < n_c && cand_sel[t]) {
            const float zv = fmaxf(cand_v[t], 0.f);
            z[(size_t)row * F + cand_i[t]] = zv;
            const int s = atomicAdd(&out_cnt, 1);
            if (s < MAXK) { wvp[s] = zv; wip[s] = cand_i[t]; }
        }
        return;
    }

    if (t == 0) { n_c_s = 0; c_hi_s = 0; out_cnt = 0; }
    __syncthreads();

    unsigned prefix = 0;
    int rem = k;
    for (int pass = 0; pass < 2; ++pass) {
        const int shift = 24 - 8 * pass;
        hist4[0][t] = 0; hist4[1][t] = 0; hist4[2][t] = 0; hist4[3][t] = 0;
        __syncthreads();
        for (int j = t; j < F; j += 256) {
            const unsigned key = fkey(zrow[j]);
            const bool inb = (pass == 0) || ((key >> (shift + 8)) == prefix);
            if (inb) atomicAdd(&hist4[wv_id][(key >> shift) & 255], 1);
        }
        __syncthreads();
        const int cnt = hist4[0][t] + hist4[1][t] + hist4[2][t] + hist4[3][t];
        int s = cnt;
        #pragma unroll
        for (int off = 1; off < 64; off <<= 1) {
            const int tmp = __shfl_down(s, off, 64);
            if (ln + off < 64) s += tmp;
        }
        if (ln == 0) waveTot[wv_id] = s;
        __syncthreads();
        int add = 0;
        #pragma unroll
        for (int w2 = 0; w2 < 4; ++w2)
            if (w2 > wv_id) add += waveTot[w2];
        const int sfx = s + add;
        const int nxt = sfx - cnt;
        if (sfx >= rem && nxt < rem) { s_bin = t; s_above = nxt; }
        __syncthreads();
        rem -= s_above;
        prefix = (prefix << 8) | (unsigned)s_bin;
        __syncthreads();
    }

    const float hiT = finv((prefix << 16) | 0xFFFFu) + DLT;
    const float loT = finv(prefix << 16) - DLT;

    for (int j = t; j < F; j += 256) {
        const float v = zrow[j];
        if (v > hiT) atomicAdd(&c_hi_s, 1);
        else if (v > loT) {
            const int s = atomicAdd(&n_c_s, 1);
            if (s < 256) { cand_i[s] = j; cand_sel[s] = 0; }
        }
    }
    __syncthreads();
    const int n_c2 = min(n_c_s, 256);

    {
        const float* xr = x + (size_t)row * D;
        for (int c = wv_id; c < n_c2; c += 4) {
            const float ex = exact_zpre(xr, Wenc, b_enc, b_dec, cand_i[c], D, ln);
            if (ln == 0) cand_v[c] = ex;
        }
    }
    __syncthreads();

    if (t == 0) {
        int need = k - c_hi_s;
        if (need > n_c2) need = n_c2;
        for (int it = 0; it < need; ++it) {
            int bi = -1; float bv = 0.f;
            for (int c = 0; c < n_c2; ++c) {
                if (cand_sel[c]) continue;
                const float v = cand_v[c];
                if (bi < 0 || v > bv || (v == bv && cand_i[c] < cand_i[bi])) {
                    bi = c; bv = v;
                }
            }
            if (bi < 0) break;
            cand_sel[bi] = 1;
        }
    }
    __syncthreads();

    {
        const float4 z4 = make_float4(0.f, 0.f, 0.f, 0.f);
        #pragma unroll
        for (int i = 0; i < NVEC; ++i) {
            const int p = t + 256 * i;
            if (p < nv4) dstz[p] = z4;
        }
    }
    __syncthreads();

    float* wvp = ws_vals + (size_t)row * MAXK;
    int*   wip = ws_idx  + (size_t)row * MAXK;
    for (int j = t; j < F; j += 256) {
        const float v = zrow[j];
        if (v > hiT) {
            const float zv = fmaxf(v, 0.f);
            z[(size_t)row * F + j] = zv;
            const int s = atomicAdd(&out_cnt, 1);
            if (s < MAXK) { wvp[s] = zv; wip[s] = j; }
        }
    }
    if (t < n_c2 && cand_sel[t]) {
        const float zv = fmaxf(cand_v[t], 0.f);
        z[(size_t)row * F + cand_i[t]] = zv;
        const int s = atomicAdd(&out_cnt, 1);
        if (s < MAXK) { wvp[s] = zv; wip[s] = cand_i[t]; }
    }
}

// ---------------------------------------------------------------------------
// Transpose W_dec [R, C] -> out [C, R], float4 on BOTH global sides.
// ---------------------------------------------------------------------------
__global__ __launch_bounds__(256)
void transpose4_kernel(const float* __restrict__ in, float* __restrict__ out,
                       int R, int C)
{
    __shared__ float tile[64][65];
    const int c0 = blockIdx.x * 64;
    const int r0 = blockIdx.y * 64;
    const int t  = threadIdx.x;
    const int tc = (t & 15) * 4;
    const int tr = t >> 4;

    #pragma unroll
    for (int i = 0; i < 4; ++i) {
        const int r = tr + i * 16;
        const float4 v = *(const float4*)(in + (size_t)(r0 + r) * C + c0 + tc);
        tile[r][tc]     = v.x;
        tile[r][tc + 1] = v.y;
        tile[r][tc + 2] = v.z;
        tile[r][tc + 3] = v.w;
    }
    __syncthreads();
    #pragma unroll
    for (int i = 0; i < 4; ++i) {
        const int c = tr + i * 16;
        float4 v;
        v.x = tile[tc]    [c];
        v.y = tile[tc + 1][c];
        v.z = tile[tc + 2][c];
        v.w = tile[tc + 3][c];
        *(float4*)(out + (size_t)(c0 + c) * R + r0 + tc) = v;
    }
}

__global__ __launch_bounds__(256)
void transpose_kernel(const float* __restrict__ in, float* __restrict__ out,
                      int R, int C)
{
    __shared__ float tile[32][33];
    const int c0 = blockIdx.x * 32;
    const int r0 = blockIdx.y * 32;
    const int tx = threadIdx.x & 31;
    const int ty = threadIdx.x >> 5;

    #pragma unroll
    for (int i = ty; i < 32; i += 8) {
        const int r = r0 + i, c = c0 + tx;
        tile[i][tx] = (r < R && c < C) ? in[(size_t)r * C + c] : 0.f;
    }
    __syncthreads();
    #pragma unroll
    for (int i = ty; i < 32; i += 8) {
        const int c = c0 + i, r = r0 + tx;
        if (c < C && r < R) out[(size_t)c * R + r] = tile[tx][i];
    }
}

// ---------------------------------------------------------------------------
// Sparse decode: x_hat[b,:] = b_dec + sum_j val_j * W_decT[idx_j,:]
// ---------------------------------------------------------------------------
__global__ __launch_bounds__(256)
void decode_kernel(const float* __restrict__ WdT, const float* __restrict__ wvals,
                   const int* __restrict__ widx, const float* __restrict__ b_dec,
                   float* __restrict__ x_hat, const int* __restrict__ k_ptr, int D)
{
    __shared__ float sv[MAXK];
    __shared__ int   si[MAXK];
    const int row = blockIdx.x;
    const int t   = threadIdx.x;
    int k = *k_ptr;
    if (k > MAXK) k = MAXK;

    if (t < MAXK) {
        sv[t] = wvals[(size_t)row * MAXK + t];
        si[t] = widx [(size_t)row * MAXK + t];
    }
    __syncthreads();

    for (int d0 = t * 4; d0 < D; d0 += 1024) {
        float4 a0 = *(const float4*)(b_dec + d0);
        float4 a1 = make_float4(0.f, 0.f, 0.f, 0.f);
        float4 a2 = make_float4(0.f, 0.f, 0.f, 0.f);
        float4 a3 = make_float4(0.f, 0.f, 0.f, 0.f);
        int j = 0;
        for (; j + 4 <= k; j += 4) {
            const float v0 = sv[j], v1 = sv[j+1], v2 = sv[j+2], v3 = sv[j+3];
            const float4 w0 = *(const float4*)(WdT + (size_t)si[j]   * D + d0);
            const float4 w1 = *(const float4*)(WdT + (size_t)si[j+1] * D + d0);
            const float4 w2 = *(const float4*)(WdT + (size_t)si[j+2] * D + d0);
            const float4 w3 = *(const float4*)(WdT + (size_t)si[j+3] * D + d0);
            a0.x = fmaf(v0, w0.x, a0.x); a0.y = fmaf(v0, w0.y, a0.y);
            a0.z = fmaf(v0, w0.z, a0.z); a0.w = fmaf(v0, w0.w, a0.w);
            a1.x = fmaf(v1, w1.x, a1.x); a1.y = fmaf(v1, w1.y, a1.y);
            a1.z = fmaf(v1, w1.z, a1.z); a1.w = fmaf(v1, w1.w, a1.w);
            a2.x = fmaf(v2, w2.x, a2.x); a2.y = fmaf(v2, w2.y, a2.y);
            a2.z = fmaf(v2, w2.z, a2.z); a2.w = fmaf(v2, w2.w, a2.w);
            a3.x = fmaf(v3, w3.x, a3.x); a3.y = fmaf(v3, w3.y, a3.y);
            a3.z = fmaf(v3, w3.z, a3.z); a3.w = fmaf(v3, w3.w, a3.w);
        }
        for (; j < k; ++j) {
            const float v0 = sv[j];
            const float4 w0 = *(const float4*)(WdT + (size_t)si[j] * D + d0);
            a0.x = fmaf(v0, w0.x, a0.x); a0.y = fmaf(v0, w0.y, a0.y);
            a0.z = fmaf(v0, w0.z, a0.z); a0.w = fmaf(v0, w0.w, a0.w);
        }
        a0.x += a1.x + a2.x + a3.x;
        a0.y += a1.y + a2.y + a3.y;
        a0.z += a1.z + a2.z + a3.z;
        a0.w += a1.w + a2.w + a3.w;
        *(float4*)(x_hat + (size_t)row * D + d0) = a0;
    }
}

// ---------------------------------------------------------------------------
extern "C" void kernel_launch(void* const* d_in, const int* in_sizes, int n_in,
                              void* d_out, int out_size, void* d_ws, size_t ws_size,
                              hipStream_t stream)
{
    const float* x     = (const float*)d_in[0];
    const float* W_enc = (const float*)d_in[1];
    const float* b_enc = (const float*)d_in[2];
    const float* W_dec = (const float*)d_in[3];
    const float* b_dec = (const float*)d_in[4];
    const int*   k_ptr = (const int*)d_in[5];

    const int F = in_sizes[2];
    const int D = in_sizes[4];
    const int B = in_sizes[0] / D;

    float* x_hat = (float*)d_out;
    float* z     = x_hat + (size_t)B * D;
    float* z_pre = z + (size_t)B * F;

    float* WdT = (float*)d_ws;                     // F*D floats
    float* wv  = WdT + (size_t)F * D;              // B*MAXK
    int*   wi  = (int*)(wv + (size_t)B * MAXK);    // B*MAXK
    char*  extra = (char*)(wi + (size_t)B * MAXK);

    const size_t base_need   = (size_t)F * D * 4 + (size_t)B * MAXK * 8;
    const size_t extra_need  = (size_t)B * D * 4 + (size_t)F * D * 4;
    const size_t filter_need = (size_t)B * 12 + (size_t)B * FCAP * 8;
    const bool use_pre = (ws_size >= base_need + extra_need) &&
                         (D % 32 == 0) && (B % 128 == 0) && (F % 256 == 0);
    const bool use_filter = use_pre &&
                            (ws_size >= base_need + extra_need + filter_need) &&
                            ((F & 3) == 0);

    if (use_pre) {
        ushort* AhiP = (ushort*)extra;
        ushort* AloP = AhiP + (size_t)B * D;
        ushort* WhiP = AloP + (size_t)B * D;
        ushort* WloP = WhiP + (size_t)F * D;

        prep_x_kernel<<<(B * (D / 8)) / 256, 256, 0, stream>>>(x, b_dec, AhiP, AloP, D);
        prep_w_kernel<<<(F * (D / 8)) / 256, 256, 0, stream>>>(W_enc, WhiP, WloP, D);

        if (use_filter) {
            float* tau_arr   = (float*)(WloP + (size_t)F * D);
            float* taulo_arr = tau_arr + B;
            int*   ccnt      = (int*)(taulo_arr + B);
            float* cvalB     = (float*)(ccnt + B);
            int*   cidxB     = (int*)(cvalB + (size_t)B * FCAP);

            tau_kernel<<<B, 256, 0, stream>>>(x, b_dec, k_ptr, tau_arr, taulo_arr,
                                              ccnt, F, D);
            encode_gemm_filter<<<dim3(F / 256, B / 128), 256, 0, stream>>>(
                AhiP, AloP, WhiP, WloP, b_enc, z_pre, taulo_arr, ccnt, cvalB, cidxB, D, F);

            if ((D % 64 == 0) && (F % 64 == 0))
                transpose4_kernel<<<dim3(F / 64, D / 64), 256, 0, stream>>>(W_dec, WdT, D, F);
            else
                transpose_kernel<<<dim3((F + 31) / 32, (D + 31) / 32), 256, 0, stream>>>(W_dec, WdT, D, F);

            const long n4 = (long)B * F / 4;
            zfill_kernel<<<2048, 256, 0, stream>>>((float4*)z, n4);

            topk_select<<<B, 256, 0, stream>>>(z_pre, z, wv, wi, k_ptr, x, W_enc,
                                               b_enc, b_dec, tau_arr, ccnt, cvalB,
                                               cidxB, F, D);
            decode_kernel<<<B, 256, 0, stream>>>(WdT, wv, wi, b_dec, x_hat, k_ptr, D);
            return;
        }

        encode_gemm_pre<<<dim3(F / 256, B / 128), 256, 0, stream>>>(
            AhiP, AloP, WhiP, WloP, b_enc, z_pre, D, F);
    } else {
        encode_gemm_bf16x3<<<dim3(F / 256, B / 128), 256, 0, stream>>>(
            x, W_enc, b_enc, b_dec, z_pre, D, F);
    }

    if ((D % 64 == 0) && (F % 64 == 0))
        transpose4_kernel<<<dim3(F / 64, D / 64), 256, 0, stream>>>(W_dec, WdT, D, F);
    else
        transpose_kernel<<<dim3((F + 31) / 32, (D + 31) / 32), 256, 0, stream>>>(W_dec, WdT, D, F);

    const int nv4  = F / 4;
    const int nvec = (nv4 + 255) / 256;
    const bool fastok = (F <= 16384) && ((F & 3) == 0);

    if (fastok) {
        if (nvec <= 4)
            topk_fast<4><<<B, 256, 0, stream>>>(z_pre, z, wv, wi, k_ptr, x, W_enc, b_enc, b_dec, F, D);
        else if (nvec <= 8)
            topk_fast<8><<<B, 256, 0, stream>>>(z_pre, z, wv, wi, k_ptr, x, W_enc, b_enc, b_dec, F, D);
        else
            topk_fast<16><<<B, 256, 0, stream>>>(z_pre, z, wv, wi, k_ptr, x, W_enc, b_enc, b_dec, F, D);
    } else {
        // generic fallback: radix path inside topk_fast handles any F via bad_s,
        // but large-F rows use the fallback directly through topk_fast<16>'s
        // guards only when F fits LDS keys; otherwise stream via topk_fast is
        // invalid -> use radix-only: reuse topk_fast fallback by forcing bad
        // is not possible here, so keep simple: topk_fast<16> covers F<=16384;
        // for larger F use the radix in topk_select-style via topk_fast guard.
        topk_fast<16><<<B, 256, 0, stream>>>(z_pre, z, wv, wi, k_ptr, x, W_enc, b_enc, b_dec, F, D);
    }

    decode_kernel<<<B, 256, 0, stream>>>(WdT, wv, wi, b_dec, x_hat, k_ptr, D);
}

// Round 8
// 1090.971 us; speedup vs baseline: 1.1096x; 1.1096x over previous
//
#include <hip/hip_runtime.h>
#include <cstdint>
#include <cfloat>
#include <cstddef>

#define MAXK 128
#define FCAP 256
#define DLT 4e-3f

typedef __attribute__((ext_vector_type(8))) short bf16x8;
typedef __attribute__((ext_vector_type(4))) float f32x4;

// ---------------------------------------------------------------------------
// split 8 fp32 -> hi-bf16 x8 (uint4) + lo-bf16 x8 (uint4)
// ---------------------------------------------------------------------------
__device__ __forceinline__ void split8(const float4& v0, const float4& v1,
                                       uint4& hp, uint4& lp)
{
    float vv[8] = {v0.x, v0.y, v0.z, v0.w, v1.x, v1.y, v1.z, v1.w};
    unsigned h[8], l[8];
    #pragma unroll
    for (int i = 0; i < 8; ++i) {
        unsigned u  = __float_as_uint(vv[i]);
        unsigned hb = u & 0xFFFF0000u;
        float lf    = vv[i] - __uint_as_float(hb);
        h[i] = u;
        l[i] = __float_as_uint(lf);
    }
    hp.x = (h[0] >> 16) | (h[1] & 0xFFFF0000u);
    hp.y = (h[2] >> 16) | (h[3] & 0xFFFF0000u);
    hp.z = (h[4] >> 16) | (h[5] & 0xFFFF0000u);
    hp.w = (h[6] >> 16) | (h[7] & 0xFFFF0000u);
    lp.x = (l[0] >> 16) | (l[1] & 0xFFFF0000u);
    lp.y = (l[2] >> 16) | (l[3] & 0xFFFF0000u);
    lp.z = (l[4] >> 16) | (l[5] & 0xFFFF0000u);
    lp.w = (l[6] >> 16) | (l[7] & 0xFFFF0000u);
}

// async global -> LDS, 16B per lane. LDS dest = wave-uniform base + lane*16.
__device__ __forceinline__ void gload_lds16(const void* g, void* l)
{
    __builtin_amdgcn_global_load_lds(
        (const __attribute__((address_space(1))) unsigned int*)g,
        (__attribute__((address_space(3))) unsigned int*)l,
        16, 0, 0);
}

// ---------------------------------------------------------------------------
// Monotonic uint key for float ordering
// ---------------------------------------------------------------------------
__device__ __forceinline__ unsigned fkey(float f)
{
    unsigned u = __float_as_uint(f);
    return u ^ ((unsigned)((int)u >> 31) | 0x80000000u);
}
__device__ __forceinline__ float finv(unsigned k)
{
    unsigned u = (k & 0x80000000u) ? (k ^ 0x80000000u) : ~k;
    return __uint_as_float(u);
}

// exact fp32 dot for feature f over one wave; valid result on ln==0 only
__device__ __forceinline__ float exact_zpre(const float* __restrict__ xr,
                                            const float* __restrict__ Wenc,
                                            const float* __restrict__ b_enc,
                                            const float* __restrict__ b_dec,
                                            int f, int D, int ln)
{
    const float* wr = Wenc + (size_t)f * D;
    float s = 0.f;
    for (int d = ln * 4; d < D; d += 256) {
        float4 xv = *(const float4*)(xr + d);
        float4 bd = *(const float4*)(b_dec + d);
        float4 wv4 = *(const float4*)(wr + d);
        s = fmaf(xv.x - bd.x, wv4.x, s);
        s = fmaf(xv.y - bd.y, wv4.y, s);
        s = fmaf(xv.z - bd.z, wv4.z, s);
        s = fmaf(xv.w - bd.w, wv4.w, s);
    }
    #pragma unroll
    for (int o = 32; o > 0; o >>= 1) s += __shfl_down(s, o, 64);
    return s + b_enc[f];
}

// ---------------------------------------------------------------------------
// prep_x: (x - b_dec) -> split bf16 hi/lo, tile-packed + pre-swizzled.
// ---------------------------------------------------------------------------
__global__ __launch_bounds__(256)
void prep_x_kernel(const float* __restrict__ x, const float* __restrict__ b_dec,
                   ushort* __restrict__ AhiP, ushort* __restrict__ AloP, int D)
{
    const int c   = blockIdx.x * 256 + threadIdx.x;
    const int t   = c >> 9;
    const int wc  = c & 511;
    const int rl  = wc >> 2;
    const int pkc = wc & 3;
    const int kc  = (pkc - (rl >> 1)) & 3;
    const int nkb = D >> 5;
    const int band = t / nkb, kblk = t - band * nkb;
    const int row = band * 128 + rl;
    const int k0  = kblk * 32 + kc * 8;

    const float* src = x + (size_t)row * D + k0;
    float4 v0 = *(const float4*)(src);
    float4 v1 = *(const float4*)(src + 4);
    const float* bd = b_dec + k0;
    float4 d0 = *(const float4*)(bd);
    float4 d1 = *(const float4*)(bd + 4);
    v0.x -= d0.x; v0.y -= d0.y; v0.z -= d0.z; v0.w -= d0.w;
    v1.x -= d1.x; v1.y -= d1.y; v1.z -= d1.z; v1.w -= d1.w;
    uint4 hp, lp;
    split8(v0, v1, hp, lp);
    const size_t off = (size_t)t * 4096 + (size_t)wc * 8;
    *(uint4*)&AhiP[off] = hp;
    *(uint4*)&AloP[off] = lp;
}

// ---------------------------------------------------------------------------
// prep_w: W_enc -> split bf16 hi/lo, tile-packed + pre-swizzled.
// ---------------------------------------------------------------------------
__global__ __launch_bounds__(256)
void prep_w_kernel(const float* __restrict__ Wenc,
                   ushort* __restrict__ WhiP, ushort* __restrict__ WloP, int D)
{
    const int c   = blockIdx.x * 256 + threadIdx.x;
    const int t   = c >> 10;
    const int wc  = c & 1023;
    const int rl  = wc >> 2;
    const int pkc = wc & 3;
    const int kc  = (pkc - (rl >> 1)) & 3;
    const int nkb = D >> 5;
    const int fband = t / nkb, kblk = t - fband * nkb;
    const int f   = fband * 256 + rl;
    const int k0  = kblk * 32 + kc * 8;

    const float* src = Wenc + (size_t)f * D + k0;
    float4 v0 = *(const float4*)(src);
    float4 v1 = *(const float4*)(src + 4);
    uint4 hp, lp;
    split8(v0, v1, hp, lp);
    const size_t off = (size_t)t * 8192 + (size_t)wc * 8;
    *(uint4*)&WhiP[off] = hp;
    *(uint4*)&WloP[off] = lp;
}

// ---------------------------------------------------------------------------
// Encode GEMM, pre-split operands: staging is pure global_load_lds DMA.
// 48 KB LDS -> 2 blocks/CU; inter-block overlap hides staging (proven config,
// round-5 best: total 1106 us).
// ---------------------------------------------------------------------------
__global__ __launch_bounds__(256, 2)
void encode_gemm_pre(const ushort* __restrict__ AhiP, const ushort* __restrict__ AloP,
                     const ushort* __restrict__ WhiP, const ushort* __restrict__ WloP,
                     const float* __restrict__ b_enc, float* __restrict__ z_pre,
                     int D, int F)
{
    __shared__ ushort AsHi[4096];
    __shared__ ushort AsLo[4096];
    __shared__ ushort BsHi[8192];
    __shared__ ushort BsLo[8192];

    const int tid = threadIdx.x;
    const int bm  = blockIdx.y * 128;
    const int bn  = blockIdx.x * 256;

    const int lane = tid & 63;
    const int w    = tid >> 6;
    const int wm   = (w >> 1) * 64;
    const int wn   = (w & 1) * 128;
    const int fr   = lane & 15;
    const int q    = lane >> 4;
    const int nkb  = D >> 5;

    int aoff[4], boff[8];
    #pragma unroll
    for (int mi = 0; mi < 4; ++mi) {
        const int r = wm + mi * 16 + fr;
        aoff[mi] = r * 32 + (((q + (r >> 1)) & 3) * 8);
    }
    #pragma unroll
    for (int ni = 0; ni < 8; ++ni) {
        const int r = wn + ni * 16 + fr;
        boff[ni] = r * 32 + (((q + (r >> 1)) & 3) * 8);
    }

    f32x4 acc[4][8];
    #pragma unroll
    for (int mi = 0; mi < 4; ++mi)
        #pragma unroll
        for (int ni = 0; ni < 8; ++ni)
            acc[mi][ni] = (f32x4){0.f, 0.f, 0.f, 0.f};

    const char* aHi = (const char*)AhiP + (size_t)blockIdx.y * nkb * 8192;
    const char* aLo = (const char*)AloP + (size_t)blockIdx.y * nkb * 8192;
    const char* bHi = (const char*)WhiP + (size_t)blockIdx.x * nkb * 16384;
    const char* bLo = (const char*)WloP + (size_t)blockIdx.x * nkb * 16384;
    const int la16 = lane * 16;

    for (int kb = 0; kb < nkb; ++kb) {
        const char* pa = aHi + (size_t)kb * 8192;
        const char* pl = aLo + (size_t)kb * 8192;
        const char* pb = bHi + (size_t)kb * 16384;
        const char* pm = bLo + (size_t)kb * 16384;

        #pragma unroll
        for (int c = 0; c < 2; ++c) {
            const int off = (w * 2 + c) * 1024;
            gload_lds16(pa + off + la16, (char*)AsHi + off);
            gload_lds16(pl + off + la16, (char*)AsLo + off);
        }
        #pragma unroll
        for (int c = 0; c < 4; ++c) {
            const int off = (w * 4 + c) * 1024;
            gload_lds16(pb + off + la16, (char*)BsHi + off);
            gload_lds16(pm + off + la16, (char*)BsLo + off);
        }
        asm volatile("s_waitcnt vmcnt(0)" ::: "memory");
        __syncthreads();

        bf16x8 ahi[4], alo[4];
        #pragma unroll
        for (int mi = 0; mi < 4; ++mi) {
            ahi[mi] = *(const bf16x8*)&AsHi[aoff[mi]];
            alo[mi] = *(const bf16x8*)&AsLo[aoff[mi]];
        }
        #pragma unroll
        for (int ni = 0; ni < 8; ++ni) {
            bf16x8 bhi = *(const bf16x8*)&BsHi[boff[ni]];
            bf16x8 blo = *(const bf16x8*)&BsLo[boff[ni]];
            #pragma unroll
            for (int mi = 0; mi < 4; ++mi) {
                acc[mi][ni] = __builtin_amdgcn_mfma_f32_16x16x32_bf16(alo[mi], bhi, acc[mi][ni], 0, 0, 0);
                acc[mi][ni] = __builtin_amdgcn_mfma_f32_16x16x32_bf16(ahi[mi], blo, acc[mi][ni], 0, 0, 0);
                acc[mi][ni] = __builtin_amdgcn_mfma_f32_16x16x32_bf16(ahi[mi], bhi, acc[mi][ni], 0, 0, 0);
            }
        }
        __syncthreads();
    }

    #pragma unroll
    for (int ni = 0; ni < 8; ++ni) {
        const int col = bn + wn + ni * 16 + fr;
        const float be = b_enc[col];
        #pragma unroll
        for (int mi = 0; mi < 4; ++mi) {
            const int rbase = bm + wm + mi * 16 + q * 4;
            float* dst = z_pre + (size_t)rbase * F + col;
            #pragma unroll
            for (int r = 0; r < 4; ++r)
                dst[(size_t)r * F] = acc[mi][ni][r] + be;
        }
    }
}

// ---------------------------------------------------------------------------
// Fallback encode GEMM (reg-staged split) — used only if workspace too small.
// ---------------------------------------------------------------------------
__global__ __launch_bounds__(256, 2)
void encode_gemm_bf16x3(const float* __restrict__ x, const float* __restrict__ Wenc,
                        const float* __restrict__ b_enc, const float* __restrict__ b_dec,
                        float* __restrict__ z_pre, int D, int F)
{
    constexpr int BM = 128, BN = 256, BK = 32;
    __shared__ ushort AsHi[BM * BK];
    __shared__ ushort AsLo[BM * BK];
    __shared__ ushort BsHi[BN * BK];
    __shared__ ushort BsLo[BN * BK];

    const int tid = threadIdx.x;
    const int bm  = blockIdx.y * BM;
    const int bn  = blockIdx.x * BN;

    const int lane = tid & 63;
    const int w    = tid >> 6;
    const int wm   = (w >> 1) * 64;
    const int wn   = (w & 1) * 128;
    const int fr   = lane & 15;
    const int q    = lane >> 4;

    int aoff[4], boff[8];
    #pragma unroll
    for (int mi = 0; mi < 4; ++mi) {
        const int r = wm + mi * 16 + fr;
        aoff[mi] = r * 32 + (((q + (r >> 1)) & 3) * 8);
    }
    #pragma unroll
    for (int ni = 0; ni < 8; ++ni) {
        const int r = wn + ni * 16 + fr;
        boff[ni] = r * 32 + (((q + (r >> 1)) & 3) * 8);
    }

    f32x4 acc[4][8];
    #pragma unroll
    for (int mi = 0; mi < 4; ++mi)
        #pragma unroll
        for (int ni = 0; ni < 8; ++ni)
            acc[mi][ni] = (f32x4){0.f, 0.f, 0.f, 0.f};

    for (int k0 = 0; k0 < D; k0 += BK) {
        #pragma unroll
        for (int j = 0; j < 2; ++j) {
            const int task = tid + 256 * j;
            const int row = task >> 2, kc = task & 3;
            const float* src = x + (size_t)(bm + row) * D + k0 + kc * 8;
            float4 v0 = *(const float4*)(src);
            float4 v1 = *(const float4*)(src + 4);
            const float* bd = b_dec + k0 + kc * 8;
            float4 d0 = *(const float4*)(bd);
            float4 d1 = *(const float4*)(bd + 4);
            v0.x -= d0.x; v0.y -= d0.y; v0.z -= d0.z; v0.w -= d0.w;
            v1.x -= d1.x; v1.y -= d1.y; v1.z -= d1.z; v1.w -= d1.w;
            uint4 hp, lp;
            split8(v0, v1, hp, lp);
            const int off = row * 32 + (((kc + (row >> 1)) & 3) * 8);
            *(uint4*)&AsHi[off] = hp;
            *(uint4*)&AsLo[off] = lp;
        }
        #pragma unroll
        for (int j = 0; j < 4; ++j) {
            const int task = tid + 256 * j;
            const int row = task >> 2, kc = task & 3;
            const float* src = Wenc + (size_t)(bn + row) * D + k0 + kc * 8;
            float4 v0 = *(const float4*)(src);
            float4 v1 = *(const float4*)(src + 4);
            uint4 hp, lp;
            split8(v0, v1, hp, lp);
            const int off = row * 32 + (((kc + (row >> 1)) & 3) * 8);
            *(uint4*)&BsHi[off] = hp;
            *(uint4*)&BsLo[off] = lp;
        }
        __syncthreads();

        bf16x8 ahi[4], alo[4];
        #pragma unroll
        for (int mi = 0; mi < 4; ++mi) {
            ahi[mi] = *(const bf16x8*)&AsHi[aoff[mi]];
            alo[mi] = *(const bf16x8*)&AsLo[aoff[mi]];
        }
        #pragma unroll
        for (int ni = 0; ni < 8; ++ni) {
            bf16x8 bhi = *(const bf16x8*)&BsHi[boff[ni]];
            bf16x8 blo = *(const bf16x8*)&BsLo[boff[ni]];
            #pragma unroll
            for (int mi = 0; mi < 4; ++mi) {
                acc[mi][ni] = __builtin_amdgcn_mfma_f32_16x16x32_bf16(alo[mi], bhi, acc[mi][ni], 0, 0, 0);
                acc[mi][ni] = __builtin_amdgcn_mfma_f32_16x16x32_bf16(ahi[mi], blo, acc[mi][ni], 0, 0, 0);
                acc[mi][ni] = __builtin_amdgcn_mfma_f32_16x16x32_bf16(ahi[mi], bhi, acc[mi][ni], 0, 0, 0);
            }
        }
        __syncthreads();
    }

    #pragma unroll
    for (int ni = 0; ni < 8; ++ni) {
        const int col = bn + wn + ni * 16 + fr;
        const float be = b_enc[col];
        #pragma unroll
        for (int mi = 0; mi < 4; ++mi) {
            const int rbase = bm + wm + mi * 16 + q * 4;
            float* dst = z_pre + (size_t)rbase * F + col;
            #pragma unroll
            for (int r = 0; r < 4; ++r)
                dst[(size_t)r * F] = acc[mi][ni][r] + be;
        }
    }
}

// ---------------------------------------------------------------------------
// topk_tau: ONE streaming pass over z_pre.
//  phase 0: sigma from ||x - b_dec||/sqrt(D) (4 KB, L2-hot); Gaussian-tail
//           tau for ~160 expected candidates; taulo = tau - 0.03*sigma.
//  phase 1: stream z_pre (read) + z zero-fill (write) + direct-compare
//           candidate collection into LDS (no keys, no second pass).
//  checks:  count(v > tau) >= k  => v_k > tau > taulo => no top-k escapes;
//           candidate count <= FCAP. Any failure -> radix fallback (correct
//           for arbitrary data).
//  then:    approx rank -> vk; sure-select > vk+DLT; exact fp32 recompute of
//           +-DLT boundary; serial pick; scatter. (Proven machinery.)
// ---------------------------------------------------------------------------
__global__ __launch_bounds__(256)
void topk_tau(const float* __restrict__ z_pre, float* __restrict__ z,
              float* __restrict__ ws_vals, int* __restrict__ ws_idx,
              const int* __restrict__ k_ptr,
              const float* __restrict__ x, const float* __restrict__ Wenc,
              const float* __restrict__ b_enc, const float* __restrict__ b_dec,
              int F, int D)
{
    const int row = blockIdx.x;
    const int t   = threadIdx.x;
    const int k   = *k_ptr;
    const int wv_id = t >> 6, ln = t & 63;

    __shared__ float s2w[4];
    __shared__ float cand_v[FCAP];
    __shared__ int   cand_i[FCAP];
    __shared__ unsigned char cand_sel[FCAP];
    __shared__ int   bnd[128];
    __shared__ int   hist4[4][256];
    __shared__ int   waveTot[4];
    __shared__ int   s_bin, s_above;
    __shared__ int   n_c_s, n_b_s, c_hi_s, out_cnt, cnt_tau_s, bad_s;
    __shared__ unsigned vk_key;
    __shared__ float tau_sh, taulo_sh;

    if (t == 0) {
        n_c_s = 0; n_b_s = 0; c_hi_s = 0; out_cnt = 0; cnt_tau_s = 0; bad_s = 0;
        vk_key = 0xFFFFFFFFu;
    }

    // ---- phase 0: sigma from x - b_dec (row-local, 4 KB) ----
    const float* xr = x + (size_t)row * D;
    float s2 = 0.f;
    if ((D & 3) == 0) {
        for (int d = t * 4; d < D; d += 1024) {
            float4 xv = *(const float4*)(xr + d);
            float4 bd = *(const float4*)(b_dec + d);
            const float a = xv.x - bd.x, b = xv.y - bd.y;
            const float c = xv.z - bd.z, e = xv.w - bd.w;
            s2 = fmaf(a, a, s2); s2 = fmaf(b, b, s2);
            s2 = fmaf(c, c, s2); s2 = fmaf(e, e, s2);
        }
    }
    #pragma unroll
    for (int o = 32; o > 0; o >>= 1) s2 += __shfl_down(s2, o, 64);
    if (ln == 0) s2w[wv_id] = s2;
    __syncthreads();

    if (t == 0) {
        const float sig = sqrtf((s2w[0] + s2w[1] + s2w[2] + s2w[3]) / (float)D);
        if (k <= 40 && F >= 4096 && sig > 1e-4f && (D & 3) == 0) {
            const float qq  = 160.f / (float)F;
            const float tt  = sqrtf(-2.f * logf(qq));
            const float phi = tt - (2.30753f + 0.27061f * tt) /
                                   (1.f + 0.99229f * tt + 0.04481f * tt * tt);
            tau_sh   = sig * phi;
            taulo_sh = tau_sh - 0.03f * sig;
        } else {
            tau_sh = -1.f; taulo_sh = FLT_MAX; bad_s = 1;
        }
    }
    __syncthreads();
    const float tau   = tau_sh;
    const float taulo = taulo_sh;

    // ---- phase 1: single stream: read z_pre, zero z, collect candidates ----
    const float* zrow = z_pre + (size_t)row * F;
    float*       zout = z + (size_t)row * F;
    const int nv4 = F >> 2;
    {
        const float4* src4 = (const float4*)zrow;
        float4* dst4 = (float4*)zout;
        const float4 zz = make_float4(0.f, 0.f, 0.f, 0.f);
        for (int p = t; p < nv4; p += 256) {
            const float4 v = src4[p];
            dst4[p] = zz;
            const float vv[4] = {v.x, v.y, v.z, v.w};
            #pragma unroll
            for (int j = 0; j < 4; ++j) {
                if (vv[j] > taulo) {
                    const int s = atomicAdd(&n_c_s, 1);
                    if (s < FCAP) { cand_v[s] = vv[j]; cand_i[s] = p * 4 + j; }
                    if (vv[j] > tau) atomicAdd(&cnt_tau_s, 1);
                }
            }
        }
        for (int p = nv4 * 4 + t; p < F; p += 256) {   // F%4 tail
            const float v = zrow[p];
            zout[p] = 0.f;
            if (v > taulo) {
                const int s = atomicAdd(&n_c_s, 1);
                if (s < FCAP) { cand_v[s] = v; cand_i[s] = p; }
                if (v > tau) atomicAdd(&cnt_tau_s, 1);
            }
        }
    }
    cand_sel[t] = 0;
    __syncthreads();

    if (t == 0 && (n_c_s > FCAP || cnt_tau_s < k)) bad_s = 1;
    __syncthreads();
    const int n_c = min(n_c_s, FCAP);

    float* wvp = ws_vals + (size_t)row * MAXK;
    int*   wip = ws_idx  + (size_t)row * MAXK;

    if (!bad_s) {
        float myv = -FLT_MAX;
        if (t < n_c) myv = cand_v[t];

        // approx rank -> kth largest among candidates
        if (t < n_c) {
            int gt = 0;
            for (int j = 0; j < n_c; ++j) gt += (cand_v[j] > myv);
            if (gt <= k - 1) atomicMin(&vk_key, fkey(myv));
        }
        __syncthreads();

        const float vkv = finv(vk_key);
        if (t < n_c) {
            if (myv > vkv + DLT) {
                cand_sel[t] = 2;
                atomicAdd(&c_hi_s, 1);
            } else if (myv > vkv - DLT) {
                const int sb = atomicAdd(&n_b_s, 1);
                if (sb < 128) bnd[sb] = t;
            }
        }
        __syncthreads();
        if (t == 0 && n_b_s > 128) bad_s = 1;
        __syncthreads();

        if (!bad_s) {
            const int n_b = n_b_s;
            for (int b2 = wv_id; b2 < n_b; b2 += 4) {
                const int c = bnd[b2];
                const float ex = exact_zpre(xr, Wenc, b_enc, b_dec, cand_i[c], D, ln);
                if (ln == 0) cand_v[c] = ex;
            }
            __syncthreads();

            if (t == 0) {
                int need = k - c_hi_s;
                if (need > n_b) need = n_b;
                for (int it = 0; it < need; ++it) {
                    int bi = -1; float bv = 0.f;
                    for (int b2 = 0; b2 < n_b; ++b2) {
                        const int c = bnd[b2];
                        if (cand_sel[c]) continue;
                        const float v = cand_v[c];
                        if (bi < 0 || v > bv || (v == bv && cand_i[c] < cand_i[bi])) {
                            bi = c; bv = v;
                        }
                    }
                    if (bi < 0) break;
                    cand_sel[bi] = 1;
                }
            }
            __syncthreads();

            if (t < n_c && cand_sel[t]) {
                const float zv = fmaxf(cand_v[t], 0.f);
                zout[cand_i[t]] = zv;
                const int s = atomicAdd(&out_cnt, 1);
                if (s < MAXK) { wvp[s] = zv; wip[s] = cand_i[t]; }
            }
            return;
        }
    }

    // ================= fallback: 2-pass radix on global z_pre ===============
    // (z already fully zero-filled by phase 1)
    if (t == 0) { n_c_s = 0; c_hi_s = 0; out_cnt = 0; }
    __syncthreads();

    unsigned prefix = 0;
    int rem = k;
    for (int pass = 0; pass < 2; ++pass) {
        const int shift = 24 - 8 * pass;
        hist4[0][t] = 0; hist4[1][t] = 0; hist4[2][t] = 0; hist4[3][t] = 0;
        __syncthreads();
        for (int j = t; j < F; j += 256) {
            const unsigned key = fkey(zrow[j]);
            const bool inb = (pass == 0) || ((key >> (shift + 8)) == prefix);
            if (inb) atomicAdd(&hist4[wv_id][(key >> shift) & 255], 1);
        }
        __syncthreads();
        const int cnt2 = hist4[0][t] + hist4[1][t] + hist4[2][t] + hist4[3][t];
        int s = cnt2;
        #pragma unroll
        for (int off = 1; off < 64; off <<= 1) {
            const int tmp = __shfl_down(s, off, 64);
            if (ln + off < 64) s += tmp;
        }
        if (ln == 0) waveTot[wv_id] = s;
        __syncthreads();
        int add = 0;
        #pragma unroll
        for (int w2 = 0; w2 < 4; ++w2)
            if (w2 > wv_id) add += waveTot[w2];
        const int sfx = s + add;
        const int nxt = sfx - cnt2;
        if (sfx >= rem && nxt < rem) { s_bin = t; s_above = nxt; }
        __syncthreads();
        rem -= s_above;
        prefix = (prefix << 8) | (unsigned)s_bin;
        __syncthreads();
    }

    const float hiT = finv((prefix << 16) | 0xFFFFu) + DLT;
    const float loT = finv(prefix << 16) - DLT;

    cand_sel[t] = 0;
    __syncthreads();
    for (int j = t; j < F; j += 256) {
        const float v = zrow[j];
        if (v > hiT) atomicAdd(&c_hi_s, 1);
        else if (v > loT) {
            const int s = atomicAdd(&n_c_s, 1);
            if (s < FCAP) { cand_i[s] = j; cand_sel[s] = 0; }
        }
    }
    __syncthreads();
    const int n_c2 = min(n_c_s, FCAP);

    for (int c = wv_id; c < n_c2; c += 4) {
        const float ex = exact_zpre(xr, Wenc, b_enc, b_dec, cand_i[c], D, ln);
        if (ln == 0) cand_v[c] = ex;
    }
    __syncthreads();

    if (t == 0) {
        int need = k - c_hi_s;
        if (need > n_c2) need = n_c2;
        for (int it = 0; it < need; ++it) {
            int bi = -1; float bv = 0.f;
            for (int c = 0; c < n_c2; ++c) {
                if (cand_sel[c]) continue;
                const float v = cand_v[c];
                if (bi < 0 || v > bv || (v == bv && cand_i[c] < cand_i[bi])) {
                    bi = c; bv = v;
                }
            }
            if (bi < 0) break;
            cand_sel[bi] = 1;
        }
    }
    __syncthreads();

    for (int j = t; j < F; j += 256) {
        const float v = zrow[j];
        if (v > hiT) {
            const float zv = fmaxf(v, 0.f);
            zout[j] = zv;
            const int s = atomicAdd(&out_cnt, 1);
            if (s < MAXK) { wvp[s] = zv; wip[s] = j; }
        }
    }
    if (t < n_c2 && cand_sel[t]) {
        const float zv = fmaxf(cand_v[t], 0.f);
        zout[cand_i[t]] = zv;
        const int s = atomicAdd(&out_cnt, 1);
        if (s < MAXK) { wvp[s] = zv; wip[s] = cand_i[t]; }
    }
}

// ---------------------------------------------------------------------------
// Transpose W_dec [R, C] -> out [C, R], float4 on BOTH global sides.
// ---------------------------------------------------------------------------
__global__ __launch_bounds__(256)
void transpose4_kernel(const float* __restrict__ in, float* __restrict__ out,
                       int R, int C)
{
    __shared__ float tile[64][65];
    const int c0 = blockIdx.x * 64;
    const int r0 = blockIdx.y * 64;
    const int t  = threadIdx.x;
    const int tc = (t & 15) * 4;
    const int tr = t >> 4;

    #pragma unroll
    for (int i = 0; i < 4; ++i) {
        const int r = tr + i * 16;
        const float4 v = *(const float4*)(in + (size_t)(r0 + r) * C + c0 + tc);
        tile[r][tc]     = v.x;
        tile[r][tc + 1] = v.y;
        tile[r][tc + 2] = v.z;
        tile[r][tc + 3] = v.w;
    }
    __syncthreads();
    #pragma unroll
    for (int i = 0; i < 4; ++i) {
        const int c = tr + i * 16;
        float4 v;
        v.x = tile[tc]    [c];
        v.y = tile[tc + 1][c];
        v.z = tile[tc + 2][c];
        v.w = tile[tc + 3][c];
        *(float4*)(out + (size_t)(c0 + c) * R + r0 + tc) = v;
    }
}

__global__ __launch_bounds__(256)
void transpose_kernel(const float* __restrict__ in, float* __restrict__ out,
                      int R, int C)
{
    __shared__ float tile[32][33];
    const int c0 = blockIdx.x * 32;
    const int r0 = blockIdx.y * 32;
    const int tx = threadIdx.x & 31;
    const int ty = threadIdx.x >> 5;

    #pragma unroll
    for (int i = ty; i < 32; i += 8) {
        const int r = r0 + i, c = c0 + tx;
        tile[i][tx] = (r < R && c < C) ? in[(size_t)r * C + c] : 0.f;
    }
    __syncthreads();
    #pragma unroll
    for (int i = ty; i < 32; i += 8) {
        const int c = c0 + i, r = r0 + tx;
        if (c < C && r < R) out[(size_t)c * R + r] = tile[tx][i];
    }
}

// ---------------------------------------------------------------------------
// Sparse decode: x_hat[b,:] = b_dec + sum_j val_j * W_decT[idx_j,:]
// ---------------------------------------------------------------------------
__global__ __launch_bounds__(256)
void decode_kernel(const float* __restrict__ WdT, const float* __restrict__ wvals,
                   const int* __restrict__ widx, const float* __restrict__ b_dec,
                   float* __restrict__ x_hat, const int* __restrict__ k_ptr, int D)
{
    __shared__ float sv[MAXK];
    __shared__ int   si[MAXK];
    const int row = blockIdx.x;
    const int t   = threadIdx.x;
    int k = *k_ptr;
    if (k > MAXK) k = MAXK;

    if (t < MAXK) {
        sv[t] = wvals[(size_t)row * MAXK + t];
        si[t] = widx [(size_t)row * MAXK + t];
    }
    __syncthreads();

    for (int d0 = t * 4; d0 < D; d0 += 1024) {
        float4 a0 = *(const float4*)(b_dec + d0);
        float4 a1 = make_float4(0.f, 0.f, 0.f, 0.f);
        float4 a2 = make_float4(0.f, 0.f, 0.f, 0.f);
        float4 a3 = make_float4(0.f, 0.f, 0.f, 0.f);
        int j = 0;
        for (; j + 4 <= k; j += 4) {
            const float v0 = sv[j], v1 = sv[j+1], v2 = sv[j+2], v3 = sv[j+3];
            const float4 w0 = *(const float4*)(WdT + (size_t)si[j]   * D + d0);
            const float4 w1 = *(const float4*)(WdT + (size_t)si[j+1] * D + d0);
            const float4 w2 = *(const float4*)(WdT + (size_t)si[j+2] * D + d0);
            const float4 w3 = *(const float4*)(WdT + (size_t)si[j+3] * D + d0);
            a0.x = fmaf(v0, w0.x, a0.x); a0.y = fmaf(v0, w0.y, a0.y);
            a0.z = fmaf(v0, w0.z, a0.z); a0.w = fmaf(v0, w0.w, a0.w);
            a1.x = fmaf(v1, w1.x, a1.x); a1.y = fmaf(v1, w1.y, a1.y);
            a1.z = fmaf(v1, w1.z, a1.z); a1.w = fmaf(v1, w1.w, a1.w);
            a2.x = fmaf(v2, w2.x, a2.x); a2.y = fmaf(v2, w2.y, a2.y);
            a2.z = fmaf(v2, w2.z, a2.z); a2.w = fmaf(v2, w2.w, a2.w);
            a3.x = fmaf(v3, w3.x, a3.x); a3.y = fmaf(v3, w3.y, a3.y);
            a3.z = fmaf(v3, w3.z, a3.z); a3.w = fmaf(v3, w3.w, a3.w);
        }
        for (; j < k; ++j) {
            const float v0 = sv[j];
            const float4 w0 = *(const float4*)(WdT + (size_t)si[j] * D + d0);
            a0.x = fmaf(v0, w0.x, a0.x); a0.y = fmaf(v0, w0.y, a0.y);
            a0.z = fmaf(v0, w0.z, a0.z); a0.w = fmaf(v0, w0.w, a0.w);
        }
        a0.x += a1.x + a2.x + a3.x;
        a0.y += a1.y + a2.y + a3.y;
        a0.z += a1.z + a2.z + a3.z;
        a0.w += a1.w + a2.w + a3.w;
        *(float4*)(x_hat + (size_t)row * D + d0) = a0;
    }
}

// ---------------------------------------------------------------------------
extern "C" void kernel_launch(void* const* d_in, const int* in_sizes, int n_in,
                              void* d_out, int out_size, void* d_ws, size_t ws_size,
                              hipStream_t stream)
{
    const float* x     = (const float*)d_in[0];
    const float* W_enc = (const float*)d_in[1];
    const float* b_enc = (const float*)d_in[2];
    const float* W_dec = (const float*)d_in[3];
    const float* b_dec = (const float*)d_in[4];
    const int*   k_ptr = (const int*)d_in[5];

    const int F = in_sizes[2];
    const int D = in_sizes[4];
    const int B = in_sizes[0] / D;

    float* x_hat = (float*)d_out;
    float* z     = x_hat + (size_t)B * D;
    float* z_pre = z + (size_t)B * F;

    float* WdT = (float*)d_ws;                     // F*D floats
    float* wv  = WdT + (size_t)F * D;              // B*MAXK
    int*   wi  = (int*)(wv + (size_t)B * MAXK);    // B*MAXK
    char*  extra = (char*)(wi + (size_t)B * MAXK);

    const size_t base_need  = (size_t)F * D * 4 + (size_t)B * MAXK * 8;
    const size_t extra_need = (size_t)B * D * 4 + (size_t)F * D * 4;
    const bool use_pre = (ws_size >= base_need + extra_need) &&
                         (D % 32 == 0) && (B % 128 == 0) && (F % 256 == 0);

    if (use_pre) {
        ushort* AhiP = (ushort*)extra;
        ushort* AloP = AhiP + (size_t)B * D;
        ushort* WhiP = AloP + (size_t)B * D;
        ushort* WloP = WhiP + (size_t)F * D;

        prep_x_kernel<<<(B * (D / 8)) / 256, 256, 0, stream>>>(x, b_dec, AhiP, AloP, D);
        prep_w_kernel<<<(F * (D / 8)) / 256, 256, 0, stream>>>(W_enc, WhiP, WloP, D);
        encode_gemm_pre<<<dim3(F / 256, B / 128), 256, 0, stream>>>(
            AhiP, AloP, WhiP, WloP, b_enc, z_pre, D, F);
    } else {
        encode_gemm_bf16x3<<<dim3(F / 256, B / 128), 256, 0, stream>>>(
            x, W_enc, b_enc, b_dec, z_pre, D, F);
    }

    if ((D % 64 == 0) && (F % 64 == 0))
        transpose4_kernel<<<dim3(F / 64, D / 64), 256, 0, stream>>>(W_dec, WdT, D, F);
    else
        transpose_kernel<<<dim3((F + 31) / 32, (D + 31) / 32), 256, 0, stream>>>(W_dec, WdT, D, F);

    topk_tau<<<B, 256, 0, stream>>>(z_pre, z, wv, wi, k_ptr, x, W_enc,
                                    b_enc, b_dec, F, D);

    decode_kernel<<<B, 256, 0, stream>>>(WdT, wv, wi, b_dec, x_hat, k_ptr, D);
}